// Round 1
// baseline (190.308 us; speedup 1.0000x reference)
//
#include <hip/hip_runtime.h>
#include <hip/hip_bf16.h>
#include <stdint.h>

#define B_ 2
#define C_ 256
#define H_ 96
#define W_ 96
#define HW_ (H_*W_)

typedef __hip_bfloat16 bf16_t;

__device__ __forceinline__ float bflo(uint32_t u){ return __uint_as_float(u << 16); }
__device__ __forceinline__ float bfhi(uint32_t u){ return __uint_as_float(u & 0xffff0000u); }

// ---------- (B, C, HW) f32  ->  (B, HW, C) bf16 tile transpose ----------
__global__ __launch_bounds__(256) void k_transpose(const float* __restrict__ in,
                                                   bf16_t* __restrict__ out) {
  __shared__ float t[32][33];
  const int b = blockIdx.z;
  const int p0 = blockIdx.x * 32, c0 = blockIdx.y * 32;
  const int tx = threadIdx.x, ty = threadIdx.y;
  const float* src = in + ((size_t)b * C_ + c0) * HW_ + p0;
#pragma unroll
  for (int i = 0; i < 4; ++i)
    t[ty + 8 * i][tx] = src[(size_t)(ty + 8 * i) * HW_ + tx];
  __syncthreads();
  bf16_t* dst = out + ((size_t)b * HW_ + p0) * C_ + c0;
#pragma unroll
  for (int i = 0; i < 4; ++i)
    dst[(size_t)(ty + 8 * i) * C_ + tx] = __float2bfloat16(t[tx][ty + 8 * i]);
}

// ---------- 2x2 avg pool on (B, h, w, C) bf16 ----------
__global__ __launch_bounds__(256) void k_pool(const bf16_t* __restrict__ in,
                                              bf16_t* __restrict__ out,
                                              int hin, int win) {
  const int wout = win >> 1, hout = hin >> 1;
  int idx = blockIdx.x;
  const int X = idx % wout; idx /= wout;
  const int Y = idx % hout; const int b = idx / hout;
  const int c = threadIdx.x;
  const bf16_t* p = in + (((size_t)b * hin + 2 * Y) * win + 2 * X) * C_ + c;
  const size_t rs = (size_t)win * C_;
  float v = __bfloat162float(p[0]) + __bfloat162float(p[C_])
          + __bfloat162float(p[rs]) + __bfloat162float(p[rs + C_]);
  out[(((size_t)b * hout + Y) * wout + X) * C_ + c] = __float2bfloat16(v * 0.25f);
}

// ---------- main: per-pixel windowed dot products + bilinear combine ----------
__global__ __launch_bounds__(256) void k_corr(const bf16_t* __restrict__ f1t,
                                              const bf16_t* __restrict__ pyr,
                                              const float* __restrict__ cent,
                                              float* __restrict__ out) {
  __shared__ float dl[4][112];
  const int wid  = threadIdx.x >> 6;   // wave in block -> one pixel per wave
  const int lane = threadIdx.x & 63;
  const int cg   = lane & 7;           // channel subgroup (8 bf16 each)
  const int pg   = lane >> 3;          // position subgroup (8 positions / instr)

  // XCD-aware swizzle: XCDs 0-3 handle batch 0, XCDs 4-7 handle batch 1,
  // so each XCD's 4MB L2 sees only one batch's level-0 map (4.7 MB bf16).
  const int g    = blockIdx.x;         // 0..4607
  const int xcd  = g & 7;
  const int slot = g >> 3;             // 0..575
  const int b    = xcd >> 2;
  const int ib   = slot * 4 + (xcd & 3);   // block-in-batch 0..2303
  const int yx   = ib * 4 + wid;
  const int pix  = b * HW_ + yx;

  const float cx = cent[(size_t)(b * 2 + 0) * HW_ + yx];
  const float cy = cent[(size_t)(b * 2 + 1) * HW_ + yx];

  // f1 vector for this pixel: lane's channel set {it*64 + cg*8 + j}, in regs,
  // pre-scaled by 1/sqrt(C) = 1/16.
  float f1r[4][8];
  {
    const bf16_t* fp = f1t + (size_t)pix * C_ + cg * 8;
#pragma unroll
    for (int it = 0; it < 4; ++it) {
      uint4 v = *reinterpret_cast<const uint4*>(fp + it * 64);
      f1r[it][0] = bflo(v.x) * 0.0625f; f1r[it][1] = bfhi(v.x) * 0.0625f;
      f1r[it][2] = bflo(v.y) * 0.0625f; f1r[it][3] = bfhi(v.y) * 0.0625f;
      f1r[it][4] = bflo(v.z) * 0.0625f; f1r[it][5] = bfhi(v.z) * 0.0625f;
      f1r[it][6] = bflo(v.w) * 0.0625f; f1r[it][7] = bfhi(v.w) * 0.0625f;
    }
  }

  constexpr size_t LOFF[4] = {
      0,
      (size_t)B_ * HW_ * C_,
      (size_t)B_ * HW_ * C_ + (size_t)B_ * (HW_ / 4) * C_,
      (size_t)B_ * HW_ * C_ + (size_t)B_ * (HW_ / 4) * C_ + (size_t)B_ * (HW_ / 16) * C_};

#pragma unroll
  for (int lvl = 0; lvl < 4; ++lvl) {
    const int hl = H_ >> lvl, wl = W_ >> lvl;
    const bf16_t* base = pyr + LOFF[lvl] + (size_t)b * hl * wl * C_;
    const float sc  = 1.0f / (float)(1 << lvl);
    const float cxl = cx * sc, cyl = cy * sc;
    const float fx = floorf(cxl), fy = floorf(cyl);
    const int X0 = (int)fx - 4, Y0 = (int)fy - 4;
    const float wx1 = cxl - fx, wy1 = cyl - fy;
    const float wx0 = 1.0f - wx1, wy0 = 1.0f - wy1;

    // 100 window positions, 8 at a time (13 groups, 4 phantom slots)
    for (int gq = 0; gq < 13; ++gq) {
      const int p = gq * 8 + pg;
      const int prow = p / 10, pcol = p - prow * 10;
      const int yy = Y0 + prow, xx = X0 + pcol;
      const bool valid = (yy >= 0) & (yy < hl) & (xx >= 0) & (xx < wl) & (p < 100);
      const int yyc = min(max(yy, 0), hl - 1);
      const int xxc = min(max(xx, 0), wl - 1);
      const bf16_t* ptr = base + (((size_t)yyc * wl + xxc) << 8) + cg * 8;
      float acc = 0.0f;
#pragma unroll
      for (int it = 0; it < 4; ++it) {
        const uint4 v = *reinterpret_cast<const uint4*>(ptr + it * 64);
        acc += bflo(v.x) * f1r[it][0] + bfhi(v.x) * f1r[it][1]
             + bflo(v.y) * f1r[it][2] + bfhi(v.y) * f1r[it][3]
             + bflo(v.z) * f1r[it][4] + bfhi(v.z) * f1r[it][5]
             + bflo(v.w) * f1r[it][6] + bfhi(v.w) * f1r[it][7];
      }
      acc = valid ? acc : 0.0f;
      // reduce over the 8 channel-lanes of this position group
      acc += __shfl_xor(acc, 1);
      acc += __shfl_xor(acc, 2);
      acc += __shfl_xor(acc, 4);
      if (cg == 0 && p < 100) dl[wid][p] = acc;
    }
    __syncthreads();

    // separable bilinear combine: out(a,b) uses d[b][a], d[b][a+1], d[b+1][a], d[b+1][a+1]
#pragma unroll
    for (int r = 0; r < 2; ++r) {
      const int o = r * 64 + lane;
      if (o < 81) {
        const int a = o / 9, bq = o - a * 9;   // a = x-offset idx (outer), bq = y-offset idx
        const float* d = dl[wid];
        const float d00 = d[bq * 10 + a],      d10 = d[bq * 10 + a + 1];
        const float d01 = d[bq * 10 + a + 10], d11 = d[bq * 10 + a + 11];
        const float v = wy0 * (wx0 * d00 + wx1 * d10) + wy1 * (wx0 * d01 + wx1 * d11);
        out[(size_t)(b * 324 + lvl * 81 + o) * HW_ + yx] = v;
      }
    }
    __syncthreads();
  }
}

extern "C" void kernel_launch(void* const* d_in, const int* in_sizes, int n_in,
                              void* d_out, int out_size, void* d_ws, size_t ws_size,
                              hipStream_t stream) {
  (void)in_sizes; (void)n_in; (void)out_size; (void)ws_size;
  const float* f1   = (const float*)d_in[0];
  const float* f2   = (const float*)d_in[1];
  const float* cent = (const float*)d_in[2];
  float* out = (float*)d_out;

  // workspace layout (bf16): f1t | L0 | L1 | L2 | L3  (~22 MB total)
  bf16_t* f1t = (bf16_t*)d_ws;
  bf16_t* L0 = f1t + (size_t)B_ * HW_ * C_;
  bf16_t* L1 = L0 + (size_t)B_ * HW_ * C_;
  bf16_t* L2 = L1 + (size_t)B_ * (HW_ / 4) * C_;
  bf16_t* L3 = L2 + (size_t)B_ * (HW_ / 16) * C_;

  dim3 tb(32, 8, 1);
  dim3 tg(HW_ / 32, C_ / 32, B_);
  hipLaunchKernelGGL(k_transpose, tg, tb, 0, stream, f1, f1t);
  hipLaunchKernelGGL(k_transpose, tg, tb, 0, stream, f2, L0);
  hipLaunchKernelGGL(k_pool, dim3(B_ * 48 * 48), dim3(256), 0, stream, L0, L1, 96, 96);
  hipLaunchKernelGGL(k_pool, dim3(B_ * 24 * 24), dim3(256), 0, stream, L1, L2, 48, 48);
  hipLaunchKernelGGL(k_pool, dim3(B_ * 12 * 12), dim3(256), 0, stream, L2, L3, 24, 24);
  hipLaunchKernelGGL(k_corr, dim3(B_ * HW_ / 4), dim3(256), 0, stream, f1t, L0, cent, out);
}